// Round 3
// baseline (8895.687 us; speedup 1.0000x reference)
//
#include <hip/hip_runtime.h>
#include <math.h>

#define SEQ    197
#define BATCH  32
#define ROWS   (BATCH * SEQ)      // 6304
#define MPAD   6400               // padded row count
#define DIM    512
#define NHEADS 8
#define NDEPTH 12
#define MLPD   2048
#define PKD    448                // patch K padded (432 real)
#define NPATCH 196
#define EPSF   1e-5f

typedef unsigned short ushort_t;
typedef __attribute__((ext_vector_type(8))) short  short8;
typedef __attribute__((ext_vector_type(4))) float  floatx4;

__device__ __forceinline__ float bf2f(ushort_t u) {
    union { unsigned int i; float f; } v; v.i = ((unsigned int)u) << 16; return v.f;
}
__device__ __forceinline__ ushort_t f2bf(float f) {
    union { float f; unsigned int i; } v; v.f = f;
    unsigned int r = v.i + 0x7fffu + ((v.i >> 16) & 1u);
    return (ushort_t)(r >> 16);
}
__device__ __forceinline__ void gl2lds16(const ushort_t* g, ushort_t* l) {
    __builtin_amdgcn_global_load_lds(
        (const __attribute__((address_space(1))) unsigned int*)g,
        (__attribute__((address_space(3))) unsigned int*)l, 16, 0, 0);
}

// ---------------------------------------------------------------------------
// Weight transpose + fp32->bf16: Wt[l][n][k] = bf16(W[l][k][n])
// ---------------------------------------------------------------------------
__global__ __launch_bounds__(256) void wtrans_kernel(
    const float* __restrict__ W, ushort_t* __restrict__ Wt, int K, int N)
{
    const int l = blockIdx.z;
    W  += (size_t)l * K * N;
    Wt += (size_t)l * K * N;
    const int n0 = blockIdx.x * 32;
    const int k0 = blockIdx.y * 32;
    const int t = threadIdx.x;

    __shared__ float tile[32][33];
    {
        const int row = t >> 3;
        const int cq  = (t & 7) * 4;
        const float4 v = *(const float4*)(W + (size_t)(k0 + row) * N + n0 + cq);
        tile[row][cq + 0] = v.x;
        tile[row][cq + 1] = v.y;
        tile[row][cq + 2] = v.z;
        tile[row][cq + 3] = v.w;
    }
    __syncthreads();
    {
        const int n  = t >> 3;
        const int kq = (t & 7) * 4;
        ushort4 o;
        o.x = f2bf(tile[kq + 0][n]);
        o.y = f2bf(tile[kq + 1][n]);
        o.z = f2bf(tile[kq + 2][n]);
        o.w = f2bf(tile[kq + 3][n]);
        *(ushort4*)(Wt + (size_t)(n0 + n) * K + k0 + kq) = o;
    }
}

// ---------------------------------------------------------------------------
// patch_w [432][512] -> pwt [512][448] bf16 (k >= 432 zero)
// ---------------------------------------------------------------------------
__global__ __launch_bounds__(256) void pwt_kernel(
    const float* __restrict__ pw, ushort_t* __restrict__ pwt)
{
    const int n = blockIdx.x;
    for (int k = threadIdx.x; k < PKD; k += 256)
        pwt[(size_t)n * PKD + k] = (k < 432) ? f2bf(pw[(size_t)k * DIM + n]) : (ushort_t)0;
}

// ---------------------------------------------------------------------------
// im2col: pcol[row][448] bf16. row = b*197 + s; s==0 (cls) or pad rows -> 0.
// col e<432: c=e/144, fy=(e%144)/12, fx=e%12 of patch p = s-1.
// ---------------------------------------------------------------------------
__global__ __launch_bounds__(256) void im2col_kernel(
    const float* __restrict__ img, ushort_t* __restrict__ pcol)
{
    const int r = blockIdx.x;
    const int t = threadIdx.x;
    ushort_t* row = pcol + (size_t)r * PKD;
    const int b = r / SEQ;
    const int s = r - b * SEQ;
    const bool valid = (r < ROWS) && (s > 0);
    const int p = s - 1;
    const int gy = p / 14, gx = p - (p / 14) * 14;

    #pragma unroll
    for (int rep = 0; rep < 2; ++rep) {
        const int e = t + rep * 256;
        if (e >= PKD) break;
        float v = 0.f;
        if (valid && e < 432) {
            const int c = e / 144;
            const int rr = e - c * 144;
            const int fy = rr / 12, fx = rr - (rr / 12) * 12;
            const int py = gy * 8 - 2 + fy;
            const int px = gx * 8 - 2 + fx;
            if (py >= 0 && py < 112 && px >= 0 && px < 112)
                v = img[((size_t)(b * 3 + c) * 112 + py) * 112 + px];
        }
        row[e] = f2bf(v);
    }
}

// ---------------------------------------------------------------------------
// pos add: x[b,s,:] += pos[s,:] (s>0); x[b,0,:] = cls + pos[0]
// ---------------------------------------------------------------------------
__global__ __launch_bounds__(256) void pos_add_kernel(
    float* __restrict__ x, const float* __restrict__ cls, const float* __restrict__ pos)
{
    const int r = blockIdx.x;
    const int t = threadIdx.x;
    const int b = r / SEQ;
    const int s = r - b * SEQ;
    float* xr = x + (size_t)r * DIM;
    const float* pr = pos + (size_t)s * DIM;
    if (s == 0) {
        xr[t]       = cls[t]       + pr[t];
        xr[t + 256] = cls[t + 256] + pr[t + 256];
    } else {
        xr[t]       += pr[t];
        xr[t + 256] += pr[t + 256];
    }
}

// ---------------------------------------------------------------------------
// Fast LayerNorm: 4 rows/block, one wave per row, no block sync. bf16 out.
// ---------------------------------------------------------------------------
__global__ __launch_bounds__(256) void ln4_kernel(
    const float* __restrict__ in, ushort_t* __restrict__ out,
    const float* __restrict__ g, const float* __restrict__ bta)
{
    const int t = threadIdx.x;
    const int w = t >> 6, lane = t & 63;
    const int r = blockIdx.x * 4 + w;
    const int off = lane * 8;
    const float* ip = in + (size_t)r * DIM + off;
    const float4 a = *(const float4*)ip;
    const float4 c = *(const float4*)(ip + 4);
    float s  = a.x + a.y + a.z + a.w + c.x + c.y + c.z + c.w;
    float ss = a.x*a.x + a.y*a.y + a.z*a.z + a.w*a.w + c.x*c.x + c.y*c.y + c.z*c.z + c.w*c.w;
    #pragma unroll
    for (int o = 32; o > 0; o >>= 1) {
        s  += __shfl_xor(s, o);
        ss += __shfl_xor(ss, o);
    }
    const float mu  = s * (1.f / 512.f);
    const float var = ss * (1.f / 512.f) - mu * mu;
    const float inv = rsqrtf(var + EPSF);
    const float4 g0 = *(const float4*)(g + off);
    const float4 g1 = *(const float4*)(g + off + 4);
    const float4 b0 = *(const float4*)(bta + off);
    const float4 b1 = *(const float4*)(bta + off + 4);
    ushort4 o0, o1;
    o0.x = f2bf((a.x - mu) * inv * g0.x + b0.x);
    o0.y = f2bf((a.y - mu) * inv * g0.y + b0.y);
    o0.z = f2bf((a.z - mu) * inv * g0.z + b0.z);
    o0.w = f2bf((a.w - mu) * inv * g0.w + b0.w);
    o1.x = f2bf((c.x - mu) * inv * g1.x + b1.x);
    o1.y = f2bf((c.y - mu) * inv * g1.y + b1.y);
    o1.z = f2bf((c.z - mu) * inv * g1.z + b1.z);
    o1.w = f2bf((c.w - mu) * inv * g1.w + b1.w);
    ushort_t* op = out + (size_t)r * DIM + off;
    *(ushort4*)op = o0;
    *(ushort4*)(op + 4) = o1;
}

// ---------------------------------------------------------------------------
// Row LayerNorm (old, for final head LN; fp32 out)
// ---------------------------------------------------------------------------
__global__ __launch_bounds__(256) void ln_kernel(
    const float* __restrict__ in, float* __restrict__ out,
    const float* __restrict__ g, const float* __restrict__ bta,
    size_t in_stride, size_t out_stride)
{
    const int r = blockIdx.x;
    const int t = threadIdx.x;
    const float* ip = in + (size_t)r * in_stride;
    const float v0 = ip[t];
    const float v1 = ip[t + 256];
    float s = v0 + v1;
    float ss = v0 * v0 + v1 * v1;
    #pragma unroll
    for (int off = 32; off > 0; off >>= 1) {
        s  += __shfl_xor(s, off);
        ss += __shfl_xor(ss, off);
    }
    __shared__ float rs[4], rss[4];
    if ((t & 63) == 0) { rs[t >> 6] = s; rss[t >> 6] = ss; }
    __syncthreads();
    s  = rs[0] + rs[1] + rs[2] + rs[3];
    ss = rss[0] + rss[1] + rss[2] + rss[3];
    const float mu  = s * (1.f / 512.f);
    const float var = ss * (1.f / 512.f) - mu * mu;
    const float inv = rsqrtf(var + EPSF);
    float* op = out + (size_t)r * out_stride;
    op[t]       = (v0 - mu) * inv * g[t]       + bta[t];
    op[t + 256] = (v1 - mu) * inv * g[t + 256] + bta[t + 256];
}

// ---------------------------------------------------------------------------
// bf16 MFMA GEMM, template BM (128 or 64), BN=128, BK=32, 256 threads.
// mode 0: Cb = bf16(acc+bias); 1: Cx += acc+bias; 2: Cb = bf16(gelu(acc+bias));
// 3: Cx = acc+bias
// ---------------------------------------------------------------------------
template <int BM>
__global__ __launch_bounds__(256) void gemm_bf16_kernel(
    const ushort_t* __restrict__ A, const ushort_t* __restrict__ Bt,
    const float* __restrict__ bias, ushort_t* __restrict__ Cb,
    float* __restrict__ Cx, int N, int K, int mode)
{
    constexpr int MI = BM / 32;          // M frags per wave (4 or 2)
    __shared__ ushort_t As[BM * 32];
    __shared__ ushort_t Bs[128 * 32];
    const int t = threadIdx.x;
    const int l = t & 63;
    const int w = t >> 6;
    const int bm = blockIdx.y * BM;
    const int bn = blockIdx.x * 128;
    const int wm = (w & 1) * (BM / 2);
    const int wn = (w >> 1) * 64;

    const ushort_t* ga;
    ushort_t* la;
    if constexpr (BM == 128) {
        ga = A + (size_t)(bm + w * 32 + (l >> 2)) * K + (l & 3) * 8;
        la = As + w * 1024;
    } else {
        ga = A + (size_t)(bm + w * 16 + (l >> 2)) * K + (l & 3) * 8;
        la = As + w * 512;
    }
    const ushort_t* gb = Bt + (size_t)(bn + w * 32 + (l >> 2)) * K + (l & 3) * 8;
    ushort_t* lb = Bs + w * 1024;
    const size_t rowK16 = (size_t)16 * K;

    floatx4 acc[MI][4];
    #pragma unroll
    for (int i = 0; i < MI; ++i)
        #pragma unroll
        for (int j = 0; j < 4; ++j)
            acc[i][j] = (floatx4){0.f, 0.f, 0.f, 0.f};

    const int fr = l & 15;
    const int kq = (l >> 4) * 8;

    for (int k0 = 0; k0 < K; k0 += 32) {
        if constexpr (BM == 128) {
            gl2lds16(ga + k0,          la);
            gl2lds16(ga + k0 + rowK16, la + 512);
        } else {
            gl2lds16(ga + k0, la);
        }
        gl2lds16(gb + k0,          lb);
        gl2lds16(gb + k0 + rowK16, lb + 512);
        __syncthreads();
        short8 af[MI], bfr[4];
        #pragma unroll
        for (int i = 0; i < MI; ++i)
            af[i] = *(const short8*)(As + (wm + i * 16 + fr) * 32 + kq);
        #pragma unroll
        for (int j = 0; j < 4; ++j)
            bfr[j] = *(const short8*)(Bs + (wn + j * 16 + fr) * 32 + kq);
        #pragma unroll
        for (int i = 0; i < MI; ++i)
            #pragma unroll
            for (int j = 0; j < 4; ++j)
                acc[i][j] = __builtin_amdgcn_mfma_f32_16x16x32_bf16(
                    af[i], bfr[j], acc[i][j], 0, 0, 0);
        __syncthreads();
    }

    float bv[4];
    #pragma unroll
    for (int j = 0; j < 4; ++j)
        bv[j] = bias ? bias[bn + wn + j * 16 + fr] : 0.f;

    const int r0 = (l >> 4) * 4;
    #pragma unroll
    for (int i = 0; i < MI; ++i)
        #pragma unroll
        for (int r = 0; r < 4; ++r) {
            const size_t row = (size_t)(bm + wm + i * 16 + r0 + r);
            if (mode == 1) {
                float* cp = Cx + row * N + bn + wn + fr;
                #pragma unroll
                for (int j = 0; j < 4; ++j)
                    cp[j * 16] += acc[i][j][r] + bv[j];
            } else if (mode == 3) {
                float* cp = Cx + row * N + bn + wn + fr;
                #pragma unroll
                for (int j = 0; j < 4; ++j)
                    cp[j * 16] = acc[i][j][r] + bv[j];
            } else if (mode == 2) {
                ushort_t* cp = Cb + row * N + bn + wn + fr;
                #pragma unroll
                for (int j = 0; j < 4; ++j) {
                    const float v = acc[i][j][r] + bv[j];
                    cp[j * 16] = f2bf(0.5f * v * (1.f + erff(v * 0.70710678118654752f)));
                }
            } else {
                ushort_t* cp = Cb + row * N + bn + wn + fr;
                #pragma unroll
                for (int j = 0; j < 4; ++j)
                    cp[j * 16] = f2bf(acc[i][j][r] + bv[j]);
            }
        }
}

// ---------------------------------------------------------------------------
// Fused attention: scores+softmax+head-mix+LN(heads)+AV per (b, 4-query tile).
// qkv bf16 rows (b*197+s)*1536: q@0, k@512, v@1024, col = h*64+d.
// Output o bf16 (b*197+i)*512, col = g*64+d.
// ---------------------------------------------------------------------------
__global__ __launch_bounds__(256) void attn_fused_kernel(
    const ushort_t* __restrict__ qkv, const float* __restrict__ rw,
    const float* __restrict__ lw, const float* __restrict__ lb,
    ushort_t* __restrict__ o)
{
    const int b  = blockIdx.x;
    const int it = blockIdx.y;       // 0..49, queries it*4..it*4+3
    const int t = threadIdx.x;
    const int w = t >> 6, lane = t & 63;

    __shared__ float S[4][8][200];   // probs then attn_ln, [ii][h|g][j]
    __shared__ float KV[197][65];    // K_h / V_g tile (fp32)
    __shared__ float qs[4][64];
    __shared__ float rws[64], lws[8], lbs[8];
    __shared__ float red_m[4][4], red_s[4][4];

    if (t < 64) rws[t] = rw[t];
    if (t < 8) { lws[t] = lw[t]; lbs[t] = lb[t]; }

    const size_t base = (size_t)(b * SEQ) * 1536;

    for (int h = 0; h < NHEADS; ++h) {
        __syncthreads();             // protect KV from previous use
        // stage K_h (bf16 -> fp32 LDS)
        for (int e = t; e < SEQ * 16; e += 256) {
            const int j = e >> 4;
            const int d4 = (e & 15) * 4;
            const ushort4 kv = *(const ushort4*)(qkv + base + (size_t)j * 1536 + 512 + h * 64 + d4);
            KV[j][d4 + 0] = bf2f(kv.x);
            KV[j][d4 + 1] = bf2f(kv.y);
            KV[j][d4 + 2] = bf2f(kv.z);
            KV[j][d4 + 3] = bf2f(kv.w);
        }
        // stage q rows (4 x 64)
        {
            const int ii = t >> 6, d = t & 63;
            const int i = it * 4 + ii;
            qs[ii][d] = (i < SEQ) ? bf2f(qkv[base + (size_t)i * 1536 + h * 64 + d]) : 0.f;
        }
        __syncthreads();

        float sv[4];
        if (t < SEQ) {
            float acc[4] = {0.f, 0.f, 0.f, 0.f};
            #pragma unroll
            for (int d4 = 0; d4 < 64; d4 += 4) {
                float4 kvv;
                kvv.x = KV[t][d4 + 0];
                kvv.y = KV[t][d4 + 1];
                kvv.z = KV[t][d4 + 2];
                kvv.w = KV[t][d4 + 3];
                #pragma unroll
                for (int ii = 0; ii < 4; ++ii) {
                    const float4 q4 = *(const float4*)(&qs[ii][d4]);
                    acc[ii] = fmaf(q4.x, kvv.x, acc[ii]);
                    acc[ii] = fmaf(q4.y, kvv.y, acc[ii]);
                    acc[ii] = fmaf(q4.z, kvv.z, acc[ii]);
                    acc[ii] = fmaf(q4.w, kvv.w, acc[ii]);
                }
            }
            #pragma unroll
            for (int ii = 0; ii < 4; ++ii) sv[ii] = acc[ii] * 0.125f;
        } else {
            #pragma unroll
            for (int ii = 0; ii < 4; ++ii) sv[ii] = -1e30f;
        }

        // block max per ii
        #pragma unroll
        for (int ii = 0; ii < 4; ++ii) {
            float m = sv[ii];
            #pragma unroll
            for (int off = 32; off > 0; off >>= 1) m = fmaxf(m, __shfl_xor(m, off));
            if (lane == 0) red_m[w][ii] = m;
        }
        __syncthreads();
        float ev[4];
        #pragma unroll
        for (int ii = 0; ii < 4; ++ii) {
            const float mx = fmaxf(fmaxf(red_m[0][ii], red_m[1][ii]),
                                   fmaxf(red_m[2][ii], red_m[3][ii]));
            ev[ii] = __expf(sv[ii] - mx);
            float s = ev[ii];
            #pragma unroll
            for (int off = 32; off > 0; off >>= 1) s += __shfl_xor(s, off);
            if (lane == 0) red_s[w][ii] = s;
        }
        __syncthreads();
        if (t < SEQ) {
            #pragma unroll
            for (int ii = 0; ii < 4; ++ii) {
                const float sm = red_s[0][ii] + red_s[1][ii] + red_s[2][ii] + red_s[3][ii];
                S[ii][h][t] = ev[ii] / sm;
            }
        }
    }
    __syncthreads();

    // head mix + LN over heads (in-place S)
    if (t < SEQ) {
        #pragma unroll
        for (int ii = 0; ii < 4; ++ii) {
            float a[8];
            #pragma unroll
            for (int h = 0; h < 8; ++h) a[h] = S[ii][h][t];
            float m[8];
            float mu = 0.f;
            #pragma unroll
            for (int g = 0; g < 8; ++g) {
                float s = 0.f;
                #pragma unroll
                for (int h = 0; h < 8; ++h) s = fmaf(a[h], rws[h * 8 + g], s);
                m[g] = s;
                mu += s;
            }
            mu *= 0.125f;
            float var = 0.f;
            #pragma unroll
            for (int g = 0; g < 8; ++g) { const float d = m[g] - mu; var = fmaf(d, d, var); }
            var *= 0.125f;
            const float inv = rsqrtf(var + EPSF);
            #pragma unroll
            for (int g = 0; g < 8; ++g)
                S[ii][g][t] = (m[g] - mu) * inv * lws[g] + lbs[g];
        }
    }

    // AV: O[ii, g*64+d] = sum_j S[ii][g][j] * V[j][g*64+d]
    const int ii = w;
    const int d = lane;
    const int i = it * 4 + ii;
    for (int g = 0; g < 8; ++g) {
        __syncthreads();             // protect KV (and first: orders mix->AV)
        for (int e = t; e < SEQ * 16; e += 256) {
            const int j = e >> 4;
            const int d4 = (e & 15) * 4;
            const ushort4 vv = *(const ushort4*)(qkv + base + (size_t)j * 1536 + 1024 + g * 64 + d4);
            KV[j][d4 + 0] = bf2f(vv.x);
            KV[j][d4 + 1] = bf2f(vv.y);
            KV[j][d4 + 2] = bf2f(vv.z);
            KV[j][d4 + 3] = bf2f(vv.w);
        }
        __syncthreads();
        float acc = 0.f;
        int j = 0;
        #pragma unroll 4
        for (; j + 4 <= SEQ; j += 4) {
            const float4 a4 = *(const float4*)(&S[ii][g][j]);
            acc = fmaf(a4.x, KV[j + 0][d], acc);
            acc = fmaf(a4.y, KV[j + 1][d], acc);
            acc = fmaf(a4.z, KV[j + 2][d], acc);
            acc = fmaf(a4.w, KV[j + 3][d], acc);
        }
        for (; j < SEQ; ++j) acc = fmaf(S[ii][g][j], KV[j][d], acc);
        if (i < SEQ)
            o[(size_t)(b * SEQ + i) * DIM + g * 64 + d] = f2bf(acc);
    }
}

// ---------------------------------------------------------------------------
extern "C" void kernel_launch(void* const* d_in, const int* in_sizes, int n_in,
                              void* d_out, int out_size, void* d_ws, size_t ws_size,
                              hipStream_t stream)
{
    (void)in_sizes; (void)n_in; (void)out_size; (void)ws_size;

    const float* img       = (const float*)d_in[0];
    const float* patch_w   = (const float*)d_in[1];
    const float* patch_b   = (const float*)d_in[2];
    const float* cls_token = (const float*)d_in[3];
    const float* pos_emb   = (const float*)d_in[4];
    const float* ln1_w     = (const float*)d_in[5];
    const float* ln1_b     = (const float*)d_in[6];
    const float* qkv_w     = (const float*)d_in[7];
    const float* reattn_w  = (const float*)d_in[8];
    const float* reattn_lw = (const float*)d_in[9];
    const float* reattn_lb = (const float*)d_in[10];
    const float* out_w     = (const float*)d_in[11];
    const float* out_b     = (const float*)d_in[12];
    const float* ln2_w     = (const float*)d_in[13];
    const float* ln2_b     = (const float*)d_in[14];
    const float* ff1_w     = (const float*)d_in[15];
    const float* ff1_b     = (const float*)d_in[16];
    const float* ff2_w     = (const float*)d_in[17];
    const float* ff2_b     = (const float*)d_in[18];
    const float* head_lw   = (const float*)d_in[19];
    const float* head_lb   = (const float*)d_in[20];
    float* out = (float*)d_out;

    // workspace layout
    char* p = (char*)d_ws;
    float* x = (float*)p;            p += (size_t)MPAD * DIM * 4;          // 13.1 MB
    ushort_t* hb = (ushort_t*)p;     p += (size_t)MPAD * DIM * 2;          // 6.6 MB
    ushort_t* qkvb = (ushort_t*)p;   p += (size_t)MPAD * 1536 * 2;         // 19.7 MB
    ushort_t* midb = (ushort_t*)p;   p += (size_t)MPAD * MLPD * 2;         // 26.2 MB
    ushort_t* pcol = (ushort_t*)p;   p += (size_t)MPAD * PKD * 2;          // 5.7 MB
    ushort_t* pwt  = (ushort_t*)p;   p += (size_t)DIM * PKD * 2;           // 0.46 MB
    ushort_t* qkv_wt = (ushort_t*)p; p += (size_t)NDEPTH * 1536 * 512 * 2;
    ushort_t* out_wt = (ushort_t*)p; p += (size_t)NDEPTH * 512 * 512 * 2;
    ushort_t* ff1_wt = (ushort_t*)p; p += (size_t)NDEPTH * 2048 * 512 * 2;
    ushort_t* ff2_wt = (ushort_t*)p; p += (size_t)NDEPTH * 512 * 2048 * 2;

    // one-time weight prep
    wtrans_kernel<<<dim3(1536 / 32, 512 / 32, NDEPTH), 256, 0, stream>>>(qkv_w, qkv_wt, 512, 1536);
    wtrans_kernel<<<dim3(512 / 32, 512 / 32, NDEPTH), 256, 0, stream>>>(out_w, out_wt, 512, 512);
    wtrans_kernel<<<dim3(2048 / 32, 512 / 32, NDEPTH), 256, 0, stream>>>(ff1_w, ff1_wt, 512, 2048);
    wtrans_kernel<<<dim3(512 / 32, 2048 / 32, NDEPTH), 256, 0, stream>>>(ff2_w, ff2_wt, 2048, 512);
    pwt_kernel<<<DIM, 256, 0, stream>>>(patch_w, pwt);

    // patch embed = im2col + GEMM + pos add
    im2col_kernel<<<MPAD, 256, 0, stream>>>(img, pcol);
    gemm_bf16_kernel<64><<<dim3(DIM / 128, MPAD / 64), 256, 0, stream>>>(
        pcol, pwt, patch_b, nullptr, x, DIM, PKD, 3);
    pos_add_kernel<<<ROWS, 256, 0, stream>>>(x, cls_token, pos_emb);

    for (int l = 0; l < NDEPTH; ++l) {
        ln4_kernel<<<ROWS / 4, 256, 0, stream>>>(x, hb, ln1_w + l * DIM, ln1_b + l * DIM);
        gemm_bf16_kernel<128><<<dim3(1536 / 128, MPAD / 128), 256, 0, stream>>>(
            hb, qkv_wt + (size_t)l * 1536 * 512, nullptr, qkvb, nullptr, 1536, 512, 0);
        attn_fused_kernel<<<dim3(BATCH, 50), 256, 0, stream>>>(
            qkvb, reattn_w + l * 64, reattn_lw + l * 8, reattn_lb + l * 8, hb);
        gemm_bf16_kernel<64><<<dim3(DIM / 128, MPAD / 64), 256, 0, stream>>>(
            hb, out_wt + (size_t)l * 512 * 512, out_b + l * DIM, nullptr, x, DIM, 512, 1);
        ln4_kernel<<<ROWS / 4, 256, 0, stream>>>(x, hb, ln2_w + l * DIM, ln2_b + l * DIM);
        gemm_bf16_kernel<128><<<dim3(MLPD / 128, MPAD / 128), 256, 0, stream>>>(
            hb, ff1_wt + (size_t)l * 2048 * 512, ff1_b + l * MLPD, midb, nullptr, MLPD, 512, 2);
        gemm_bf16_kernel<64><<<dim3(DIM / 128, MPAD / 64), 256, 0, stream>>>(
            midb, ff2_wt + (size_t)l * 512 * 2048, ff2_b + l * DIM, nullptr, x, DIM, 2048, 1);
    }

    ln_kernel<<<BATCH, 256, 0, stream>>>(x, out, head_lw, head_lb, (size_t)SEQ * DIM, DIM);
}

// Round 4
// 2790.229 us; speedup vs baseline: 3.1882x; 3.1882x over previous
//
#include <hip/hip_runtime.h>
#include <math.h>

#define SEQ    197
#define BATCH  32
#define ROWS   (BATCH * SEQ)      // 6304
#define MPAD   6400               // padded row count
#define DIM    512
#define NHEADS 8
#define NDEPTH 12
#define MLPD   2048
#define PKD    448                // patch K padded (432 real)
#define SP     208                // padded seq for attention (13 x 16)
#define PSTR   224                // Pm col stride (7 x 32)
#define VSTR   228                // Vt LDS row stride (bank-conflict pad)
#define EPSF   1e-5f

typedef unsigned short ushort_t;
typedef __attribute__((ext_vector_type(8))) short  short8;
typedef __attribute__((ext_vector_type(4))) float  floatx4;

__device__ __forceinline__ float bf2f(ushort_t u) {
    union { unsigned int i; float f; } v; v.i = ((unsigned int)u) << 16; return v.f;
}
__device__ __forceinline__ ushort_t f2bf(float f) {
    union { float f; unsigned int i; } v; v.f = f;
    unsigned int r = v.i + 0x7fffu + ((v.i >> 16) & 1u);
    return (ushort_t)(r >> 16);
}
__device__ __forceinline__ void gl2lds16(const ushort_t* g, ushort_t* l) {
    __builtin_amdgcn_global_load_lds(
        (const __attribute__((address_space(1))) unsigned int*)g,
        (__attribute__((address_space(3))) unsigned int*)l, 16, 0, 0);
}

// ---------------------------------------------------------------------------
// Weight transpose + fp32->bf16: Wt[l][n][k] = bf16(W[l][k][n])
// ---------------------------------------------------------------------------
__global__ __launch_bounds__(256) void wtrans_kernel(
    const float* __restrict__ W, ushort_t* __restrict__ Wt, int K, int N)
{
    const int l = blockIdx.z;
    W  += (size_t)l * K * N;
    Wt += (size_t)l * K * N;
    const int n0 = blockIdx.x * 32;
    const int k0 = blockIdx.y * 32;
    const int t = threadIdx.x;

    __shared__ float tile[32][33];
    {
        const int row = t >> 3;
        const int cq  = (t & 7) * 4;
        const float4 v = *(const float4*)(W + (size_t)(k0 + row) * N + n0 + cq);
        tile[row][cq + 0] = v.x;
        tile[row][cq + 1] = v.y;
        tile[row][cq + 2] = v.z;
        tile[row][cq + 3] = v.w;
    }
    __syncthreads();
    {
        const int n  = t >> 3;
        const int kq = (t & 7) * 4;
        ushort4 o;
        o.x = f2bf(tile[kq + 0][n]);
        o.y = f2bf(tile[kq + 1][n]);
        o.z = f2bf(tile[kq + 2][n]);
        o.w = f2bf(tile[kq + 3][n]);
        *(ushort4*)(Wt + (size_t)(n0 + n) * K + k0 + kq) = o;
    }
}

// ---------------------------------------------------------------------------
// patch_w [432][512] -> pwt [512][448] bf16 (k >= 432 zero)
// ---------------------------------------------------------------------------
__global__ __launch_bounds__(256) void pwt_kernel(
    const float* __restrict__ pw, ushort_t* __restrict__ pwt)
{
    const int n = blockIdx.x;
    for (int k = threadIdx.x; k < PKD; k += 256)
        pwt[(size_t)n * PKD + k] = (k < 432) ? f2bf(pw[(size_t)k * DIM + n]) : (ushort_t)0;
}

// ---------------------------------------------------------------------------
// im2col: pcol[row][448] bf16. row = b*197 + s; s==0 (cls) or pad rows -> 0.
// ---------------------------------------------------------------------------
__global__ __launch_bounds__(256) void im2col_kernel(
    const float* __restrict__ img, ushort_t* __restrict__ pcol)
{
    const int r = blockIdx.x;
    const int t = threadIdx.x;
    ushort_t* row = pcol + (size_t)r * PKD;
    const int b = r / SEQ;
    const int s = r - b * SEQ;
    const bool valid = (r < ROWS) && (s > 0);
    const int p = s - 1;
    const int gy = p / 14, gx = p - (p / 14) * 14;

    #pragma unroll
    for (int rep = 0; rep < 2; ++rep) {
        const int e = t + rep * 256;
        if (e >= PKD) break;
        float v = 0.f;
        if (valid && e < 432) {
            const int c = e / 144;
            const int rr = e - c * 144;
            const int fy = rr / 12, fx = rr - (rr / 12) * 12;
            const int py = gy * 8 - 2 + fy;
            const int px = gx * 8 - 2 + fx;
            if (py >= 0 && py < 112 && px >= 0 && px < 112)
                v = img[((size_t)(b * 3 + c) * 112 + py) * 112 + px];
        }
        row[e] = f2bf(v);
    }
}

// ---------------------------------------------------------------------------
// pos add: x[b,s,:] += pos[s,:] (s>0); x[b,0,:] = cls + pos[0]
// ---------------------------------------------------------------------------
__global__ __launch_bounds__(256) void pos_add_kernel(
    float* __restrict__ x, const float* __restrict__ cls, const float* __restrict__ pos)
{
    const int r = blockIdx.x;
    const int t = threadIdx.x;
    const int b = r / SEQ;
    const int s = r - b * SEQ;
    float* xr = x + (size_t)r * DIM;
    const float* pr = pos + (size_t)s * DIM;
    if (s == 0) {
        xr[t]       = cls[t]       + pr[t];
        xr[t + 256] = cls[t + 256] + pr[t + 256];
    } else {
        xr[t]       += pr[t];
        xr[t + 256] += pr[t + 256];
    }
}

// ---------------------------------------------------------------------------
// Fast LayerNorm: 4 rows/block, one wave per row, bf16 out.
// ---------------------------------------------------------------------------
__global__ __launch_bounds__(256) void ln4_kernel(
    const float* __restrict__ in, ushort_t* __restrict__ out,
    const float* __restrict__ g, const float* __restrict__ bta)
{
    const int t = threadIdx.x;
    const int w = t >> 6, lane = t & 63;
    const int r = blockIdx.x * 4 + w;
    const int off = lane * 8;
    const float* ip = in + (size_t)r * DIM + off;
    const float4 a = *(const float4*)ip;
    const float4 c = *(const float4*)(ip + 4);
    float s  = a.x + a.y + a.z + a.w + c.x + c.y + c.z + c.w;
    float ss = a.x*a.x + a.y*a.y + a.z*a.z + a.w*a.w + c.x*c.x + c.y*c.y + c.z*c.z + c.w*c.w;
    #pragma unroll
    for (int o = 32; o > 0; o >>= 1) {
        s  += __shfl_xor(s, o);
        ss += __shfl_xor(ss, o);
    }
    const float mu  = s * (1.f / 512.f);
    const float var = ss * (1.f / 512.f) - mu * mu;
    const float inv = rsqrtf(var + EPSF);
    const float4 g0 = *(const float4*)(g + off);
    const float4 g1 = *(const float4*)(g + off + 4);
    const float4 b0 = *(const float4*)(bta + off);
    const float4 b1 = *(const float4*)(bta + off + 4);
    ushort4 o0, o1;
    o0.x = f2bf((a.x - mu) * inv * g0.x + b0.x);
    o0.y = f2bf((a.y - mu) * inv * g0.y + b0.y);
    o0.z = f2bf((a.z - mu) * inv * g0.z + b0.z);
    o0.w = f2bf((a.w - mu) * inv * g0.w + b0.w);
    o1.x = f2bf((c.x - mu) * inv * g1.x + b1.x);
    o1.y = f2bf((c.y - mu) * inv * g1.y + b1.y);
    o1.z = f2bf((c.z - mu) * inv * g1.z + b1.z);
    o1.w = f2bf((c.w - mu) * inv * g1.w + b1.w);
    ushort_t* op = out + (size_t)r * DIM + off;
    *(ushort4*)op = o0;
    *(ushort4*)(op + 4) = o1;
}

// ---------------------------------------------------------------------------
// Row LayerNorm (final head LN; fp32 out)
// ---------------------------------------------------------------------------
__global__ __launch_bounds__(256) void ln_kernel(
    const float* __restrict__ in, float* __restrict__ out,
    const float* __restrict__ g, const float* __restrict__ bta,
    size_t in_stride, size_t out_stride)
{
    const int r = blockIdx.x;
    const int t = threadIdx.x;
    const float* ip = in + (size_t)r * in_stride;
    const float v0 = ip[t];
    const float v1 = ip[t + 256];
    float s = v0 + v1;
    float ss = v0 * v0 + v1 * v1;
    #pragma unroll
    for (int off = 32; off > 0; off >>= 1) {
        s  += __shfl_xor(s, off);
        ss += __shfl_xor(ss, off);
    }
    __shared__ float rs[4], rss[4];
    if ((t & 63) == 0) { rs[t >> 6] = s; rss[t >> 6] = ss; }
    __syncthreads();
    s  = rs[0] + rs[1] + rs[2] + rs[3];
    ss = rss[0] + rss[1] + rss[2] + rss[3];
    const float mu  = s * (1.f / 512.f);
    const float var = ss * (1.f / 512.f) - mu * mu;
    const float inv = rsqrtf(var + EPSF);
    float* op = out + (size_t)r * out_stride;
    op[t]       = (v0 - mu) * inv * g[t]       + bta[t];
    op[t + 256] = (v1 - mu) * inv * g[t + 256] + bta[t + 256];
}

// ---------------------------------------------------------------------------
// bf16 MFMA GEMM, template BM (128 or 64), BN=128, BK=32, 256 threads.
// mode 0: Cb = bf16(acc+bias); 1: Cx += acc+bias; 2: Cb = bf16(gelu(acc+bias));
// 3: Cx = acc+bias
// ---------------------------------------------------------------------------
template <int BM>
__global__ __launch_bounds__(256) void gemm_bf16_kernel(
    const ushort_t* __restrict__ A, const ushort_t* __restrict__ Bt,
    const float* __restrict__ bias, ushort_t* __restrict__ Cb,
    float* __restrict__ Cx, int N, int K, int mode)
{
    constexpr int MI = BM / 32;
    __shared__ ushort_t As[BM * 32];
    __shared__ ushort_t Bs[128 * 32];
    const int t = threadIdx.x;
    const int l = t & 63;
    const int w = t >> 6;
    const int bm = blockIdx.y * BM;
    const int bn = blockIdx.x * 128;
    const int wm = (w & 1) * (BM / 2);
    const int wn = (w >> 1) * 64;

    const ushort_t* ga;
    ushort_t* la;
    if constexpr (BM == 128) {
        ga = A + (size_t)(bm + w * 32 + (l >> 2)) * K + (l & 3) * 8;
        la = As + w * 1024;
    } else {
        ga = A + (size_t)(bm + w * 16 + (l >> 2)) * K + (l & 3) * 8;
        la = As + w * 512;
    }
    const ushort_t* gb = Bt + (size_t)(bn + w * 32 + (l >> 2)) * K + (l & 3) * 8;
    ushort_t* lb = Bs + w * 1024;
    const size_t rowK16 = (size_t)16 * K;

    floatx4 acc[MI][4];
    #pragma unroll
    for (int i = 0; i < MI; ++i)
        #pragma unroll
        for (int j = 0; j < 4; ++j)
            acc[i][j] = (floatx4){0.f, 0.f, 0.f, 0.f};

    const int fr = l & 15;
    const int kq = (l >> 4) * 8;

    for (int k0 = 0; k0 < K; k0 += 32) {
        if constexpr (BM == 128) {
            gl2lds16(ga + k0,          la);
            gl2lds16(ga + k0 + rowK16, la + 512);
        } else {
            gl2lds16(ga + k0, la);
        }
        gl2lds16(gb + k0,          lb);
        gl2lds16(gb + k0 + rowK16, lb + 512);
        __syncthreads();
        short8 af[MI], bfr[4];
        #pragma unroll
        for (int i = 0; i < MI; ++i)
            af[i] = *(const short8*)(As + (wm + i * 16 + fr) * 32 + kq);
        #pragma unroll
        for (int j = 0; j < 4; ++j)
            bfr[j] = *(const short8*)(Bs + (wn + j * 16 + fr) * 32 + kq);
        #pragma unroll
        for (int i = 0; i < MI; ++i)
            #pragma unroll
            for (int j = 0; j < 4; ++j)
                acc[i][j] = __builtin_amdgcn_mfma_f32_16x16x32_bf16(
                    af[i], bfr[j], acc[i][j], 0, 0, 0);
        __syncthreads();
    }

    float bv[4];
    #pragma unroll
    for (int j = 0; j < 4; ++j)
        bv[j] = bias ? bias[bn + wn + j * 16 + fr] : 0.f;

    const int r0 = (l >> 4) * 4;
    #pragma unroll
    for (int i = 0; i < MI; ++i)
        #pragma unroll
        for (int r = 0; r < 4; ++r) {
            const size_t row = (size_t)(bm + wm + i * 16 + r0 + r);
            if (mode == 1) {
                float* cp = Cx + row * N + bn + wn + fr;
                #pragma unroll
                for (int j = 0; j < 4; ++j)
                    cp[j * 16] += acc[i][j][r] + bv[j];
            } else if (mode == 3) {
                float* cp = Cx + row * N + bn + wn + fr;
                #pragma unroll
                for (int j = 0; j < 4; ++j)
                    cp[j * 16] = acc[i][j][r] + bv[j];
            } else if (mode == 2) {
                ushort_t* cp = Cb + row * N + bn + wn + fr;
                #pragma unroll
                for (int j = 0; j < 4; ++j) {
                    const float v = acc[i][j][r] + bv[j];
                    cp[j * 16] = f2bf(0.5f * v * (1.f + erff(v * 0.70710678118654752f)));
                }
            } else {
                ushort_t* cp = Cb + row * N + bn + wn + fr;
                #pragma unroll
                for (int j = 0; j < 4; ++j)
                    cp[j * 16] = f2bf(acc[i][j][r] + bv[j]);
            }
        }
}

// ---------------------------------------------------------------------------
// QK^T + softmax via MFMA. One block per (b,h). P fp32 [bh][208][208].
// Rows i>=197 are garbage (never read); cols j>=197 masked to prob 0.
// ---------------------------------------------------------------------------
__global__ __launch_bounds__(256) void qk_softmax_kernel(
    const ushort_t* __restrict__ qkv, float* __restrict__ P)
{
    const int bh = blockIdx.x;
    const int b = bh >> 3, h = bh & 7;
    const int t = threadIdx.x;
    const int w = t >> 6, lane = t & 63;
    const int fr = lane & 15, quad = lane >> 4;

    __shared__ ushort_t Qs[SP * 64];
    __shared__ ushort_t Ks[SP * 64];

    const size_t base = (size_t)(b * SEQ) * 1536;
    for (int e = t; e < SP * 16; e += 256) {
        const int r = e >> 4;
        const int d4 = (e & 15) * 4;
        const size_t go = base + (size_t)r * 1536 + h * 64 + d4;
        *(ushort4*)(Qs + r * 64 + d4) = *(const ushort4*)(qkv + go);
        *(ushort4*)(Ks + r * 64 + d4) = *(const ushort4*)(qkv + go + 512);
    }
    __syncthreads();

    #pragma unroll
    for (int mi = 0; mi < 4; ++mi) {
        const int mf = w * 4 + mi;
        if (mf >= 13) break;
        const short8 a0 = *(const short8*)(Qs + (mf * 16 + fr) * 64 + quad * 8);
        const short8 a1 = *(const short8*)(Qs + (mf * 16 + fr) * 64 + 32 + quad * 8);
        floatx4 acc[13];
        #pragma unroll
        for (int nf = 0; nf < 13; ++nf) {
            const short8 b0 = *(const short8*)(Ks + (nf * 16 + fr) * 64 + quad * 8);
            const short8 b1 = *(const short8*)(Ks + (nf * 16 + fr) * 64 + 32 + quad * 8);
            floatx4 z = (floatx4){0.f, 0.f, 0.f, 0.f};
            z = __builtin_amdgcn_mfma_f32_16x16x32_bf16(a0, b0, z, 0, 0, 0);
            acc[nf] = __builtin_amdgcn_mfma_f32_16x16x32_bf16(a1, b1, z, 0, 0, 0);
        }
        #pragma unroll
        for (int rr = 0; rr < 4; ++rr) {
            const bool maskc = (fr >= 5);   // nf==12 invalid cols
            float mx = -1e30f;
            #pragma unroll
            for (int nf = 0; nf < 13; ++nf) {
                const float v = (nf == 12 && maskc) ? -1e30f : acc[nf][rr] * 0.125f;
                mx = fmaxf(mx, v);
            }
            #pragma unroll
            for (int off = 1; off < 16; off <<= 1) mx = fmaxf(mx, __shfl_xor(mx, off));
            float sum = 0.f;
            #pragma unroll
            for (int nf = 0; nf < 13; ++nf) {
                const float v = (nf == 12 && maskc) ? -1e30f : acc[nf][rr] * 0.125f;
                const float pe = __expf(v - mx);
                acc[nf][rr] = pe;
                sum += pe;
            }
            #pragma unroll
            for (int off = 1; off < 16; off <<= 1) sum += __shfl_xor(sum, off);
            const float inv = 1.f / sum;
            const int i = mf * 16 + quad * 4 + rr;
            float* prow = P + ((size_t)bh * SP + i) * SP + fr;
            #pragma unroll
            for (int nf = 0; nf < 13; ++nf)
                prow[nf * 16] = acc[nf][rr] * inv;
        }
    }
}

// ---------------------------------------------------------------------------
// Head mix + LN over heads: P fp32 -> Pm bf16 [b][g][208][224].
// Block per (i, b); thread j. Cols j>=197 -> 0 (so AV K-pad contributes 0).
// ---------------------------------------------------------------------------
__global__ __launch_bounds__(256) void mix_ln_kernel(
    const float* __restrict__ P, const float* __restrict__ rw,
    const float* __restrict__ lw, const float* __restrict__ lb,
    ushort_t* __restrict__ Pm)
{
    const int i = blockIdx.x;
    const int b = blockIdx.y;
    const int t = threadIdx.x;

    __shared__ float rws[64], lws[8], lbs[8];
    if (t < 64) rws[t] = rw[t];
    if (t < 8) { lws[t] = lw[t]; lbs[t] = lb[t]; }
    __syncthreads();

    float o[8];
    #pragma unroll
    for (int g = 0; g < 8; ++g) o[g] = 0.f;

    if (t < SEQ) {
        float a[8];
        #pragma unroll
        for (int h = 0; h < 8; ++h)
            a[h] = P[(((size_t)(b * 8 + h)) * SP + i) * SP + t];
        float m[8];
        float mu = 0.f;
        #pragma unroll
        for (int g = 0; g < 8; ++g) {
            float s = 0.f;
            #pragma unroll
            for (int h = 0; h < 8; ++h) s = fmaf(a[h], rws[h * 8 + g], s);
            m[g] = s;
            mu += s;
        }
        mu *= 0.125f;
        float var = 0.f;
        #pragma unroll
        for (int g = 0; g < 8; ++g) { const float d = m[g] - mu; var = fmaf(d, d, var); }
        var *= 0.125f;
        const float inv = rsqrtf(var + EPSF);
        #pragma unroll
        for (int g = 0; g < 8; ++g)
            o[g] = (m[g] - mu) * inv * lws[g] + lbs[g];
    }
    if (t < PSTR) {
        #pragma unroll
        for (int g = 0; g < 8; ++g)
            Pm[(((size_t)(b * 8 + g)) * SP + i) * PSTR + t] = f2bf(o[g]);
    }
}

// ---------------------------------------------------------------------------
// AV via MFMA: O[b,g] = Pm[b,g] (208x224) @ V[b,g] (224x64, cols>=197 zero).
// One block per (b,g). V transposed into LDS once; Pm chunked via gl2lds.
// Output bf16 into hb rows, col g*64+d.
// ---------------------------------------------------------------------------
__global__ __launch_bounds__(256) void av_kernel(
    const ushort_t* __restrict__ Pm, const ushort_t* __restrict__ qkv,
    ushort_t* __restrict__ o)
{
    const int bg = blockIdx.x;
    const int b = bg >> 3, g = bg & 7;
    const int t = threadIdx.x;
    const int w = t >> 6, lane = t & 63;
    const int fr = lane & 15, quad = lane >> 4;

    __shared__ ushort_t Vt[64 * VSTR];   // [d][j], stride 228
    __shared__ ushort_t As[SP * 32];     // [row][32k]

    // zero Vt (covers j>=197 pad)
    for (int e = t; e < 64 * VSTR / 4; e += 256)
        *(ushort4*)(Vt + e * 4) = (ushort4){0, 0, 0, 0};
    __syncthreads();

    // transpose V into Vt: lane d = t&63, j-quad = (t>>6)*4 + round*16
    const size_t vbase = (size_t)(b * SEQ) * 1536 + 1024 + g * 64;
    {
        const int d = t & 63;
        for (int j4 = (t >> 6) * 4; j4 < SEQ; j4 += 16) {
            ushort4 vv;
            vv.x = qkv[vbase + (size_t)(j4 + 0) * 1536 + d];
            vv.y = (j4 + 1 < SEQ) ? qkv[vbase + (size_t)(j4 + 1) * 1536 + d] : (ushort_t)0;
            vv.z = (j4 + 2 < SEQ) ? qkv[vbase + (size_t)(j4 + 2) * 1536 + d] : (ushort_t)0;
            vv.w = (j4 + 3 < SEQ) ? qkv[vbase + (size_t)(j4 + 3) * 1536 + d] : (ushort_t)0;
            *(ushort4*)(Vt + d * VSTR + j4) = vv;
        }
    }

    const ushort_t* gp = Pm + (size_t)bg * SP * PSTR;
    floatx4 acc[4][4];
    #pragma unroll
    for (int i = 0; i < 4; ++i)
        #pragma unroll
        for (int j = 0; j < 4; ++j)
            acc[i][j] = (floatx4){0.f, 0.f, 0.f, 0.f};

    const int nmf = (w < 3) ? 4 : 1;

    for (int k0 = 0; k0 < PSTR; k0 += 32) {
        __syncthreads();
        #pragma unroll
        for (int rr = 0; rr < 4; ++rr) {
            const int row0 = (rr * 4 + w) * 16;
            if (row0 < SP)
                gl2lds16(gp + (size_t)(row0 + (lane >> 2)) * PSTR + k0 + (lane & 3) * 8,
                         As + row0 * 32);
        }
        __syncthreads();
        for (int mi = 0; mi < nmf; ++mi) {
            const int mf = w * 4 + mi;
            const short8 af = *(const short8*)(As + (mf * 16 + fr) * 32 + quad * 8);
            #pragma unroll
            for (int nf = 0; nf < 4; ++nf) {
                const short8 bfr = *(const short8*)(Vt + (nf * 16 + fr) * VSTR + k0 + quad * 8);
                acc[mi][nf] = __builtin_amdgcn_mfma_f32_16x16x32_bf16(af, bfr, acc[mi][nf], 0, 0, 0);
            }
        }
    }

    for (int mi = 0; mi < nmf; ++mi) {
        const int mf = w * 4 + mi;
        #pragma unroll
        for (int rr = 0; rr < 4; ++rr) {
            const int i = mf * 16 + quad * 4 + rr;
            if (i < SEQ) {
                ushort_t* op = o + (size_t)(b * SEQ + i) * DIM + g * 64 + fr;
                #pragma unroll
                for (int nf = 0; nf < 4; ++nf)
                    op[nf * 16] = f2bf(acc[mi][nf][rr]);
            }
        }
    }
}

// ---------------------------------------------------------------------------
extern "C" void kernel_launch(void* const* d_in, const int* in_sizes, int n_in,
                              void* d_out, int out_size, void* d_ws, size_t ws_size,
                              hipStream_t stream)
{
    (void)in_sizes; (void)n_in; (void)out_size; (void)ws_size;

    const float* img       = (const float*)d_in[0];
    const float* patch_w   = (const float*)d_in[1];
    const float* patch_b   = (const float*)d_in[2];
    const float* cls_token = (const float*)d_in[3];
    const float* pos_emb   = (const float*)d_in[4];
    const float* ln1_w     = (const float*)d_in[5];
    const float* ln1_b     = (const float*)d_in[6];
    const float* qkv_w     = (const float*)d_in[7];
    const float* reattn_w  = (const float*)d_in[8];
    const float* reattn_lw = (const float*)d_in[9];
    const float* reattn_lb = (const float*)d_in[10];
    const float* out_w     = (const float*)d_in[11];
    const float* out_b     = (const float*)d_in[12];
    const float* ln2_w     = (const float*)d_in[13];
    const float* ln2_b     = (const float*)d_in[14];
    const float* ff1_w     = (const float*)d_in[15];
    const float* ff1_b     = (const float*)d_in[16];
    const float* ff2_w     = (const float*)d_in[17];
    const float* ff2_b     = (const float*)d_in[18];
    const float* head_lw   = (const float*)d_in[19];
    const float* head_lb   = (const float*)d_in[20];
    float* out = (float*)d_out;

    // workspace layout
    char* p = (char*)d_ws;
    float* x = (float*)p;            p += (size_t)MPAD * DIM * 4;          // 13.1 MB
    ushort_t* hb = (ushort_t*)p;     p += (size_t)MPAD * DIM * 2;          // 6.6 MB
    ushort_t* qkvb = (ushort_t*)p;   p += (size_t)MPAD * 1536 * 2;         // 19.7 MB
    char* big = p;                   // P (44.3MB) + Pm (23.9MB); midb aliases P
    float* P = (float*)big;
    ushort_t* Pm = (ushort_t*)(big + (size_t)256 * SP * SP * 4);
    ushort_t* midb = (ushort_t*)big;
    p += (size_t)256 * SP * SP * 4 + (size_t)256 * SP * PSTR * 2;          // 68.2 MB
    ushort_t* pcol = (ushort_t*)p;   p += (size_t)MPAD * PKD * 2;          // 5.7 MB
    ushort_t* pwt  = (ushort_t*)p;   p += (size_t)DIM * PKD * 2;           // 0.46 MB
    ushort_t* qkv_wt = (ushort_t*)p; p += (size_t)NDEPTH * 1536 * 512 * 2;
    ushort_t* out_wt = (ushort_t*)p; p += (size_t)NDEPTH * 512 * 512 * 2;
    ushort_t* ff1_wt = (ushort_t*)p; p += (size_t)NDEPTH * 2048 * 512 * 2;
    ushort_t* ff2_wt = (ushort_t*)p; p += (size_t)NDEPTH * 512 * 2048 * 2;

    // one-time weight prep
    wtrans_kernel<<<dim3(1536 / 32, 512 / 32, NDEPTH), 256, 0, stream>>>(qkv_w, qkv_wt, 512, 1536);
    wtrans_kernel<<<dim3(512 / 32, 512 / 32, NDEPTH), 256, 0, stream>>>(out_w, out_wt, 512, 512);
    wtrans_kernel<<<dim3(2048 / 32, 512 / 32, NDEPTH), 256, 0, stream>>>(ff1_w, ff1_wt, 512, 2048);
    wtrans_kernel<<<dim3(512 / 32, 2048 / 32, NDEPTH), 256, 0, stream>>>(ff2_w, ff2_wt, 2048, 512);
    pwt_kernel<<<DIM, 256, 0, stream>>>(patch_w, pwt);

    // patch embed = im2col + GEMM + pos add
    im2col_kernel<<<MPAD, 256, 0, stream>>>(img, pcol);
    gemm_bf16_kernel<64><<<dim3(DIM / 128, MPAD / 64), 256, 0, stream>>>(
        pcol, pwt, patch_b, nullptr, x, DIM, PKD, 3);
    pos_add_kernel<<<ROWS, 256, 0, stream>>>(x, cls_token, pos_emb);

    for (int l = 0; l < NDEPTH; ++l) {
        ln4_kernel<<<ROWS / 4, 256, 0, stream>>>(x, hb, ln1_w + l * DIM, ln1_b + l * DIM);
        gemm_bf16_kernel<128><<<dim3(1536 / 128, MPAD / 128), 256, 0, stream>>>(
            hb, qkv_wt + (size_t)l * 1536 * 512, nullptr, qkvb, nullptr, 1536, 512, 0);
        qk_softmax_kernel<<<BATCH * NHEADS, 256, 0, stream>>>(qkvb, P);
        mix_ln_kernel<<<dim3(SEQ, BATCH), 256, 0, stream>>>(
            P, reattn_w + l * 64, reattn_lw + l * 8, reattn_lb + l * 8, Pm);
        av_kernel<<<BATCH * NHEADS, 256, 0, stream>>>(Pm, qkvb, hb);
        gemm_bf16_kernel<64><<<dim3(DIM / 128, MPAD / 64), 256, 0, stream>>>(
            hb, out_wt + (size_t)l * 512 * 512, out_b + l * DIM, nullptr, x, DIM, 512, 1);
        ln4_kernel<<<ROWS / 4, 256, 0, stream>>>(x, hb, ln2_w + l * DIM, ln2_b + l * DIM);
        gemm_bf16_kernel<128><<<dim3(MLPD / 128, MPAD / 128), 256, 0, stream>>>(
            hb, ff1_wt + (size_t)l * 2048 * 512, ff1_b + l * MLPD, midb, nullptr, MLPD, 512, 2);
        gemm_bf16_kernel<64><<<dim3(DIM / 128, MPAD / 64), 256, 0, stream>>>(
            midb, ff2_wt + (size_t)l * 512 * 2048, ff2_b + l * DIM, nullptr, x, DIM, 2048, 1);
    }

    ln_kernel<<<BATCH, 256, 0, stream>>>(x, out, head_lw, head_lb, (size_t)SEQ * DIM, DIM);
}

// Round 5
// 2142.182 us; speedup vs baseline: 4.1526x; 1.3025x over previous
//
#include <hip/hip_runtime.h>
#include <math.h>

#define SEQ    197
#define BATCH  32
#define ROWS   (BATCH * SEQ)      // 6304
#define MPAD   6400               // padded row count
#define DIM    512
#define NHEADS 8
#define NDEPTH 12
#define MLPD   2048
#define PKD    448                // patch K padded (432 real), 7 x 64
#define SP     208                // padded seq for attention (13 x 16)
#define PSTR   224                // Pm col stride (7 x 32)
#define VSTR   228                // Vt LDS row stride
#define EPSF   1e-5f

typedef unsigned short ushort_t;
typedef __attribute__((ext_vector_type(8))) short  short8;
typedef __attribute__((ext_vector_type(4))) float  floatx4;

__device__ __forceinline__ float bf2f(ushort_t u) {
    union { unsigned int i; float f; } v; v.i = ((unsigned int)u) << 16; return v.f;
}
__device__ __forceinline__ ushort_t f2bf(float f) {
    union { float f; unsigned int i; } v; v.f = f;
    unsigned int r = v.i + 0x7fffu + ((v.i >> 16) & 1u);
    return (ushort_t)(r >> 16);
}
__device__ __forceinline__ void gl2lds16(const ushort_t* g, ushort_t* l) {
    __builtin_amdgcn_global_load_lds(
        (const __attribute__((address_space(1))) unsigned int*)g,
        (__attribute__((address_space(3))) unsigned int*)l, 16, 0, 0);
}
__device__ __forceinline__ float gelu_tanh(float v) {
    const float y = 0.7978845608028654f * fmaf(0.044715f * v, v * v, v);
    const float e = __expf(-2.f * fabsf(y));
    const float th = copysignf((1.f - e) * __builtin_amdgcn_rcpf(1.f + e), y);
    return 0.5f * v * (1.f + th);
}

// ---------------------------------------------------------------------------
// Weight transpose + fp32->bf16: Wt[l][n][k] = bf16(W[l][k][n])
// ---------------------------------------------------------------------------
__global__ __launch_bounds__(256) void wtrans_kernel(
    const float* __restrict__ W, ushort_t* __restrict__ Wt, int K, int N)
{
    const int l = blockIdx.z;
    W  += (size_t)l * K * N;
    Wt += (size_t)l * K * N;
    const int n0 = blockIdx.x * 32;
    const int k0 = blockIdx.y * 32;
    const int t = threadIdx.x;

    __shared__ float tile[32][33];
    {
        const int row = t >> 3;
        const int cq  = (t & 7) * 4;
        const float4 v = *(const float4*)(W + (size_t)(k0 + row) * N + n0 + cq);
        tile[row][cq + 0] = v.x;
        tile[row][cq + 1] = v.y;
        tile[row][cq + 2] = v.z;
        tile[row][cq + 3] = v.w;
    }
    __syncthreads();
    {
        const int n  = t >> 3;
        const int kq = (t & 7) * 4;
        ushort4 o;
        o.x = f2bf(tile[kq + 0][n]);
        o.y = f2bf(tile[kq + 1][n]);
        o.z = f2bf(tile[kq + 2][n]);
        o.w = f2bf(tile[kq + 3][n]);
        *(ushort4*)(Wt + (size_t)(n0 + n) * K + k0 + kq) = o;
    }
}

// ---------------------------------------------------------------------------
// patch_w [432][512] -> pwt [512][448] bf16 (k >= 432 zero)
// ---------------------------------------------------------------------------
__global__ __launch_bounds__(256) void pwt_kernel(
    const float* __restrict__ pw, ushort_t* __restrict__ pwt)
{
    const int n = blockIdx.x;
    for (int k = threadIdx.x; k < PKD; k += 256)
        pwt[(size_t)n * PKD + k] = (k < 432) ? f2bf(pw[(size_t)k * DIM + n]) : (ushort_t)0;
}

// ---------------------------------------------------------------------------
// im2col: pcol[row][448] bf16.
// ---------------------------------------------------------------------------
__global__ __launch_bounds__(256) void im2col_kernel(
    const float* __restrict__ img, ushort_t* __restrict__ pcol)
{
    const int r = blockIdx.x;
    const int t = threadIdx.x;
    ushort_t* row = pcol + (size_t)r * PKD;
    const int b = r / SEQ;
    const int s = r - b * SEQ;
    const bool valid = (r < ROWS) && (s > 0);
    const int p = s - 1;
    const int gy = p / 14, gx = p - (p / 14) * 14;

    #pragma unroll
    for (int rep = 0; rep < 2; ++rep) {
        const int e = t + rep * 256;
        if (e >= PKD) break;
        float v = 0.f;
        if (valid && e < 432) {
            const int c = e / 144;
            const int rr = e - c * 144;
            const int fy = rr / 12, fx = rr - (rr / 12) * 12;
            const int py = gy * 8 - 2 + fy;
            const int px = gx * 8 - 2 + fx;
            if (py >= 0 && py < 112 && px >= 0 && px < 112)
                v = img[((size_t)(b * 3 + c) * 112 + py) * 112 + px];
        }
        row[e] = f2bf(v);
    }
}

// ---------------------------------------------------------------------------
// pos add
// ---------------------------------------------------------------------------
__global__ __launch_bounds__(256) void pos_add_kernel(
    float* __restrict__ x, const float* __restrict__ cls, const float* __restrict__ pos)
{
    const int r = blockIdx.x;
    const int t = threadIdx.x;
    const int b = r / SEQ;
    const int s = r - b * SEQ;
    float* xr = x + (size_t)r * DIM;
    const float* pr = pos + (size_t)s * DIM;
    if (s == 0) {
        xr[t]       = cls[t]       + pr[t];
        xr[t + 256] = cls[t + 256] + pr[t + 256];
    } else {
        xr[t]       += pr[t];
        xr[t + 256] += pr[t + 256];
    }
}

// ---------------------------------------------------------------------------
// Fast LayerNorm: 4 rows/block, one wave per row, bf16 out.
// ---------------------------------------------------------------------------
__global__ __launch_bounds__(256) void ln4_kernel(
    const float* __restrict__ in, ushort_t* __restrict__ out,
    const float* __restrict__ g, const float* __restrict__ bta)
{
    const int t = threadIdx.x;
    const int w = t >> 6, lane = t & 63;
    const int r = blockIdx.x * 4 + w;
    const int off = lane * 8;
    const float* ip = in + (size_t)r * DIM + off;
    const float4 a = *(const float4*)ip;
    const float4 c = *(const float4*)(ip + 4);
    float s  = a.x + a.y + a.z + a.w + c.x + c.y + c.z + c.w;
    float ss = a.x*a.x + a.y*a.y + a.z*a.z + a.w*a.w + c.x*c.x + c.y*c.y + c.z*c.z + c.w*c.w;
    #pragma unroll
    for (int o = 32; o > 0; o >>= 1) {
        s  += __shfl_xor(s, o);
        ss += __shfl_xor(ss, o);
    }
    const float mu  = s * (1.f / 512.f);
    const float var = ss * (1.f / 512.f) - mu * mu;
    const float inv = rsqrtf(var + EPSF);
    const float4 g0 = *(const float4*)(g + off);
    const float4 g1 = *(const float4*)(g + off + 4);
    const float4 b0 = *(const float4*)(bta + off);
    const float4 b1 = *(const float4*)(bta + off + 4);
    ushort4 o0, o1;
    o0.x = f2bf((a.x - mu) * inv * g0.x + b0.x);
    o0.y = f2bf((a.y - mu) * inv * g0.y + b0.y);
    o0.z = f2bf((a.z - mu) * inv * g0.z + b0.z);
    o0.w = f2bf((a.w - mu) * inv * g0.w + b0.w);
    o1.x = f2bf((c.x - mu) * inv * g1.x + b1.x);
    o1.y = f2bf((c.y - mu) * inv * g1.y + b1.y);
    o1.z = f2bf((c.z - mu) * inv * g1.z + b1.z);
    o1.w = f2bf((c.w - mu) * inv * g1.w + b1.w);
    ushort_t* op = out + (size_t)r * DIM + off;
    *(ushort4*)op = o0;
    *(ushort4*)(op + 4) = o1;
}

// ---------------------------------------------------------------------------
// Row LayerNorm (final head LN; fp32 out)
// ---------------------------------------------------------------------------
__global__ __launch_bounds__(256) void ln_kernel(
    const float* __restrict__ in, float* __restrict__ out,
    const float* __restrict__ g, const float* __restrict__ bta,
    size_t in_stride, size_t out_stride)
{
    const int r = blockIdx.x;
    const int t = threadIdx.x;
    const float* ip = in + (size_t)r * in_stride;
    const float v0 = ip[t];
    const float v1 = ip[t + 256];
    float s = v0 + v1;
    float ss = v0 * v0 + v1 * v1;
    #pragma unroll
    for (int off = 32; off > 0; off >>= 1) {
        s  += __shfl_xor(s, off);
        ss += __shfl_xor(ss, off);
    }
    __shared__ float rs[4], rss[4];
    if ((t & 63) == 0) { rs[t >> 6] = s; rss[t >> 6] = ss; }
    __syncthreads();
    s  = rs[0] + rs[1] + rs[2] + rs[3];
    ss = rss[0] + rss[1] + rss[2] + rss[3];
    const float mu  = s * (1.f / 512.f);
    const float var = ss * (1.f / 512.f) - mu * mu;
    const float inv = rsqrtf(var + EPSF);
    float* op = out + (size_t)r * out_stride;
    op[t]       = (v0 - mu) * inv * g[t]       + bta[t];
    op[t + 256] = (v1 - mu) * inv * g[t + 256] + bta[t + 256];
}

// ---------------------------------------------------------------------------
// bf16 MFMA GEMM, BK=64, XOR-swizzled LDS staging (conflict-free ds_read_b128).
// LDS row = 64 ushorts (128B). Lane i of gl2lds fetches global chunk
// (i&7)^(row&7) so LDS[row][c] = global[row][c^(row&7)]; reads XOR back.
// mode 0: Cb=bf16(acc+bias); 1: Cx+=acc+bias; 2: Cb=bf16(gelu); 3: Cx=acc+bias
// ---------------------------------------------------------------------------
template <int BM>
__global__ __launch_bounds__(256) void gemm_bf16_kernel(
    const ushort_t* __restrict__ A, const ushort_t* __restrict__ Bt,
    const float* __restrict__ bias, ushort_t* __restrict__ Cb,
    float* __restrict__ Cx, int N, int K, int mode)
{
    constexpr int RA = BM / 4;           // A rows staged per wave
    constexpr int MI = BM / 32;          // M frags per wave
    __shared__ ushort_t As[BM * 64];
    __shared__ ushort_t Bs[128 * 64];
    const int t = threadIdx.x;
    const int l = t & 63;
    const int w = t >> 6;
    const int bm = blockIdx.y * BM;
    const int bn = blockIdx.x * 128;
    const int wm = (w & 1) * (BM / 2);
    const int wn = (w >> 1) * 64;

    const int srow = l >> 3;                 // row within 8-row group
    const int skw  = ((l & 7) ^ srow) * 8;   // swizzled k offset (ushorts)
    const ushort_t* gA = A  + (size_t)(bm + w * RA + srow) * K + skw;
    const ushort_t* gB = Bt + (size_t)(bn + w * 32 + srow) * K + skw;

    floatx4 acc[MI][4];
    #pragma unroll
    for (int i = 0; i < MI; ++i)
        #pragma unroll
        for (int j = 0; j < 4; ++j)
            acc[i][j] = (floatx4){0.f, 0.f, 0.f, 0.f};

    const int fr = l & 15;
    const int quad = l >> 4;
    const int c0 = ((quad ^ (fr & 7)) * 8);  // half-0 chunk offset; half-1 = c0^32

    for (int k0 = 0; k0 < K; k0 += 64) {
        #pragma unroll
        for (int jc = 0; jc < RA / 8; ++jc)
            gl2lds16(gA + (size_t)(jc * 8) * K + k0, As + (w * RA + jc * 8) * 64);
        #pragma unroll
        for (int jc = 0; jc < 4; ++jc)
            gl2lds16(gB + (size_t)(jc * 8) * K + k0, Bs + (w * 32 + jc * 8) * 64);
        __syncthreads();
        #pragma unroll
        for (int half = 0; half < 2; ++half) {
            const int co = c0 ^ (half * 32);
            short8 af[MI], bf4[4];
            #pragma unroll
            for (int i = 0; i < MI; ++i)
                af[i] = *(const short8*)(As + (wm + i * 16 + fr) * 64 + co);
            #pragma unroll
            for (int j = 0; j < 4; ++j)
                bf4[j] = *(const short8*)(Bs + (wn + j * 16 + fr) * 64 + co);
            #pragma unroll
            for (int i = 0; i < MI; ++i)
                #pragma unroll
                for (int j = 0; j < 4; ++j)
                    acc[i][j] = __builtin_amdgcn_mfma_f32_16x16x32_bf16(
                        af[i], bf4[j], acc[i][j], 0, 0, 0);
        }
        __syncthreads();
    }

    float bv[4];
    #pragma unroll
    for (int j = 0; j < 4; ++j)
        bv[j] = bias ? bias[bn + wn + j * 16 + fr] : 0.f;

    const int r0 = quad * 4;
    #pragma unroll
    for (int i = 0; i < MI; ++i)
        #pragma unroll
        for (int r = 0; r < 4; ++r) {
            const size_t row = (size_t)(bm + wm + i * 16 + r0 + r);
            if (mode == 1) {
                float* cp = Cx + row * N + bn + wn + fr;
                #pragma unroll
                for (int j = 0; j < 4; ++j)
                    cp[j * 16] += acc[i][j][r] + bv[j];
            } else if (mode == 3) {
                float* cp = Cx + row * N + bn + wn + fr;
                #pragma unroll
                for (int j = 0; j < 4; ++j)
                    cp[j * 16] = acc[i][j][r] + bv[j];
            } else if (mode == 2) {
                ushort_t* cp = Cb + row * N + bn + wn + fr;
                #pragma unroll
                for (int j = 0; j < 4; ++j)
                    cp[j * 16] = f2bf(gelu_tanh(acc[i][j][r] + bv[j]));
            } else {
                ushort_t* cp = Cb + row * N + bn + wn + fr;
                #pragma unroll
                for (int j = 0; j < 4; ++j)
                    cp[j * 16] = f2bf(acc[i][j][r] + bv[j]);
            }
        }
}

// ---------------------------------------------------------------------------
// QK^T + softmax via MFMA. Block per (b,h, i-half). P fp32 [bh][208][208].
// half 0: query frags 0..6, half 1: 7..12. Cols j>=197 masked.
// ---------------------------------------------------------------------------
__global__ __launch_bounds__(256) void qk_softmax_kernel(
    const ushort_t* __restrict__ qkv, float* __restrict__ P)
{
    const int bh = blockIdx.x;
    const int hf = blockIdx.y;
    const int b = bh >> 3, h = bh & 7;
    const int t = threadIdx.x;
    const int w = t >> 6, lane = t & 63;
    const int fr = lane & 15, quad = lane >> 4;
    const int cnt = hf ? 6 : 7;          // m-frags this block
    const int q0 = hf * 112;             // first query row

    __shared__ ushort_t Qs[112 * 64];
    __shared__ ushort_t Ks[SP * 64];

    const size_t base = (size_t)(b * SEQ) * 1536;
    for (int e = t; e < SP * 16; e += 256) {
        const int r = e >> 4;
        const int d4 = (e & 15) * 4;
        *(ushort4*)(Ks + r * 64 + d4) =
            *(const ushort4*)(qkv + base + (size_t)r * 1536 + 512 + h * 64 + d4);
    }
    for (int e = t; e < 112 * 16; e += 256) {
        const int r = e >> 4;
        const int d4 = (e & 15) * 4;
        *(ushort4*)(Qs + r * 64 + d4) =
            *(const ushort4*)(qkv + base + (size_t)(q0 + r) * 1536 + h * 64 + d4);
    }
    __syncthreads();

    #pragma unroll
    for (int mi = 0; mi < 2; ++mi) {
        const int mfl = w * 2 + mi;
        if (mfl >= cnt) break;
        const int mf = hf * 7 + mfl;
        const short8 a0 = *(const short8*)(Qs + (mfl * 16 + fr) * 64 + quad * 8);
        const short8 a1 = *(const short8*)(Qs + (mfl * 16 + fr) * 64 + 32 + quad * 8);
        floatx4 acc[13];
        #pragma unroll
        for (int nf = 0; nf < 13; ++nf) {
            const short8 b0 = *(const short8*)(Ks + (nf * 16 + fr) * 64 + quad * 8);
            const short8 b1 = *(const short8*)(Ks + (nf * 16 + fr) * 64 + 32 + quad * 8);
            floatx4 z = (floatx4){0.f, 0.f, 0.f, 0.f};
            z = __builtin_amdgcn_mfma_f32_16x16x32_bf16(a0, b0, z, 0, 0, 0);
            acc[nf] = __builtin_amdgcn_mfma_f32_16x16x32_bf16(a1, b1, z, 0, 0, 0);
        }
        #pragma unroll
        for (int rr = 0; rr < 4; ++rr) {
            const bool maskc = (fr >= 5);
            float mx = -1e30f;
            #pragma unroll
            for (int nf = 0; nf < 13; ++nf) {
                const float v = (nf == 12 && maskc) ? -1e30f : acc[nf][rr] * 0.125f;
                mx = fmaxf(mx, v);
            }
            #pragma unroll
            for (int off = 1; off < 16; off <<= 1) mx = fmaxf(mx, __shfl_xor(mx, off));
            float sum = 0.f;
            #pragma unroll
            for (int nf = 0; nf < 13; ++nf) {
                const float v = (nf == 12 && maskc) ? -1e30f : acc[nf][rr] * 0.125f;
                const float pe = __expf(v - mx);
                acc[nf][rr] = pe;
                sum += pe;
            }
            #pragma unroll
            for (int off = 1; off < 16; off <<= 1) sum += __shfl_xor(sum, off);
            const float inv = 1.f / sum;
            const int i = mf * 16 + quad * 4 + rr;
            float* prow = P + ((size_t)bh * SP + i) * SP + fr;
            #pragma unroll
            for (int nf = 0; nf < 13; ++nf)
                prow[nf * 16] = acc[nf][rr] * inv;
        }
    }
}

// ---------------------------------------------------------------------------
// Head mix + LN over heads: P fp32 -> Pm bf16 [b][g][208][224].
// ---------------------------------------------------------------------------
__global__ __launch_bounds__(256) void mix_ln_kernel(
    const float* __restrict__ P, const float* __restrict__ rw,
    const float* __restrict__ lw, const float* __restrict__ lb,
    ushort_t* __restrict__ Pm)
{
    const int i = blockIdx.x;
    const int b = blockIdx.y;
    const int t = threadIdx.x;

    __shared__ float rws[64], lws[8], lbs[8];
    if (t < 64) rws[t] = rw[t];
    if (t < 8) { lws[t] = lw[t]; lbs[t] = lb[t]; }
    __syncthreads();

    float o[8];
    #pragma unroll
    for (int g = 0; g < 8; ++g) o[g] = 0.f;

    if (t < SEQ) {
        float a[8];
        #pragma unroll
        for (int h = 0; h < 8; ++h)
            a[h] = P[(((size_t)(b * 8 + h)) * SP + i) * SP + t];
        float m[8];
        float mu = 0.f;
        #pragma unroll
        for (int g = 0; g < 8; ++g) {
            float s = 0.f;
            #pragma unroll
            for (int h = 0; h < 8; ++h) s = fmaf(a[h], rws[h * 8 + g], s);
            m[g] = s;
            mu += s;
        }
        mu *= 0.125f;
        float var = 0.f;
        #pragma unroll
        for (int g = 0; g < 8; ++g) { const float d = m[g] - mu; var = fmaf(d, d, var); }
        var *= 0.125f;
        const float inv = rsqrtf(var + EPSF);
        #pragma unroll
        for (int g = 0; g < 8; ++g)
            o[g] = (m[g] - mu) * inv * lws[g] + lbs[g];
    }
    if (t < PSTR) {
        #pragma unroll
        for (int g = 0; g < 8; ++g)
            Pm[(((size_t)(b * 8 + g)) * SP + i) * PSTR + t] = f2bf(o[g]);
    }
}

// ---------------------------------------------------------------------------
// AV via MFMA: block per (b,g, i-half). O = Pm (rows) @ V.
// ---------------------------------------------------------------------------
__global__ __launch_bounds__(256) void av_kernel(
    const ushort_t* __restrict__ Pm, const ushort_t* __restrict__ qkv,
    ushort_t* __restrict__ o)
{
    const int bg = blockIdx.x;
    const int hf = blockIdx.y;
    const int b = bg >> 3, g = bg & 7;
    const int t = threadIdx.x;
    const int w = t >> 6, lane = t & 63;
    const int fr = lane & 15, quad = lane >> 4;
    const int cnt = hf ? 6 : 7;
    const int q0 = hf * 112;

    __shared__ ushort_t Vt[64 * VSTR];
    __shared__ ushort_t As[112 * 32];

    for (int e = t; e < 64 * VSTR / 4; e += 256)
        *(ushort4*)(Vt + e * 4) = (ushort4){0, 0, 0, 0};
    __syncthreads();

    const size_t vbase = (size_t)(b * SEQ) * 1536 + 1024 + g * 64;
    {
        const int d = t & 63;
        for (int j4 = (t >> 6) * 4; j4 < SEQ; j4 += 16) {
            ushort4 vv;
            vv.x = qkv[vbase + (size_t)(j4 + 0) * 1536 + d];
            vv.y = (j4 + 1 < SEQ) ? qkv[vbase + (size_t)(j4 + 1) * 1536 + d] : (ushort_t)0;
            vv.z = (j4 + 2 < SEQ) ? qkv[vbase + (size_t)(j4 + 2) * 1536 + d] : (ushort_t)0;
            vv.w = (j4 + 3 < SEQ) ? qkv[vbase + (size_t)(j4 + 3) * 1536 + d] : (ushort_t)0;
            *(ushort4*)(Vt + d * VSTR + j4) = vv;
        }
    }

    const ushort_t* gp = Pm + (size_t)bg * SP * PSTR + (size_t)q0 * PSTR;
    floatx4 acc[2][4];
    #pragma unroll
    for (int i = 0; i < 2; ++i)
        #pragma unroll
        for (int j = 0; j < 4; ++j)
            acc[i][j] = (floatx4){0.f, 0.f, 0.f, 0.f};

    for (int k0 = 0; k0 < PSTR; k0 += 32) {
        __syncthreads();
        #pragma unroll
        for (int rr = 0; rr < 2; ++rr) {
            const int row0 = (rr * 4 + w) * 16;
            if (row0 < cnt * 16)
                gl2lds16(gp + (size_t)(row0 + (lane >> 2)) * PSTR + k0 + (lane & 3) * 8,
                         As + row0 * 32);
        }
        __syncthreads();
        #pragma unroll
        for (int mi = 0; mi < 2; ++mi) {
            const int mfl = w + mi * 4;
            if (mfl >= cnt) break;
            const short8 af = *(const short8*)(As + (mfl * 16 + fr) * 32 + quad * 8);
            #pragma unroll
            for (int nf = 0; nf < 4; ++nf) {
                const short8 bfr = *(const short8*)(Vt + (nf * 16 + fr) * VSTR + k0 + quad * 8);
                acc[mi][nf] = __builtin_amdgcn_mfma_f32_16x16x32_bf16(af, bfr, acc[mi][nf], 0, 0, 0);
            }
        }
    }

    #pragma unroll
    for (int mi = 0; mi < 2; ++mi) {
        const int mfl = w + mi * 4;
        if (mfl >= cnt) break;
        #pragma unroll
        for (int rr = 0; rr < 4; ++rr) {
            const int i = (hf * 7 + mfl) * 16 + quad * 4 + rr;
            if (i < SEQ) {
                ushort_t* op = o + (size_t)(b * SEQ + i) * DIM + g * 64 + fr;
                #pragma unroll
                for (int nf = 0; nf < 4; ++nf)
                    op[nf * 16] = f2bf(acc[mi][nf][rr]);
            }
        }
    }
}

// ---------------------------------------------------------------------------
extern "C" void kernel_launch(void* const* d_in, const int* in_sizes, int n_in,
                              void* d_out, int out_size, void* d_ws, size_t ws_size,
                              hipStream_t stream)
{
    (void)in_sizes; (void)n_in; (void)out_size; (void)ws_size;

    const float* img       = (const float*)d_in[0];
    const float* patch_w   = (const float*)d_in[1];
    const float* patch_b   = (const float*)d_in[2];
    const float* cls_token = (const float*)d_in[3];
    const float* pos_emb   = (const float*)d_in[4];
    const float* ln1_w     = (const float*)d_in[5];
    const float* ln1_b     = (const float*)d_in[6];
    const float* qkv_w     = (const float*)d_in[7];
    const float* reattn_w  = (const float*)d_in[8];
    const float* reattn_lw = (const float*)d_in[9];
    const float* reattn_lb = (const float*)d_in[10];
    const float* out_w     = (const float*)d_in[11];
    const float* out_b     = (const float*)d_in[12];
    const float* ln2_w     = (const float*)d_in[13];
    const float* ln2_b     = (const float*)d_in[14];
    const float* ff1_w     = (const float*)d_in[15];
    const float* ff1_b     = (const float*)d_in[16];
    const float* ff2_w     = (const float*)d_in[17];
    const float* ff2_b     = (const float*)d_in[18];
    const float* head_lw   = (const float*)d_in[19];
    const float* head_lb   = (const float*)d_in[20];
    float* out = (float*)d_out;

    // workspace layout
    char* p = (char*)d_ws;
    float* x = (float*)p;            p += (size_t)MPAD * DIM * 4;
    ushort_t* hb = (ushort_t*)p;     p += (size_t)MPAD * DIM * 2;
    ushort_t* qkvb = (ushort_t*)p;   p += (size_t)MPAD * 1536 * 2;
    char* big = p;
    float* P = (float*)big;
    ushort_t* Pm = (ushort_t*)(big + (size_t)256 * SP * SP * 4);
    ushort_t* midb = (ushort_t*)big;
    p += (size_t)256 * SP * SP * 4 + (size_t)256 * SP * PSTR * 2;
    ushort_t* pcol = (ushort_t*)p;   p += (size_t)MPAD * PKD * 2;
    ushort_t* pwt  = (ushort_t*)p;   p += (size_t)DIM * PKD * 2;
    ushort_t* qkv_wt = (ushort_t*)p; p += (size_t)NDEPTH * 1536 * 512 * 2;
    ushort_t* out_wt = (ushort_t*)p; p += (size_t)NDEPTH * 512 * 512 * 2;
    ushort_t* ff1_wt = (ushort_t*)p; p += (size_t)NDEPTH * 2048 * 512 * 2;
    ushort_t* ff2_wt = (ushort_t*)p; p += (size_t)NDEPTH * 512 * 2048 * 2;

    // one-time weight prep
    wtrans_kernel<<<dim3(1536 / 32, 512 / 32, NDEPTH), 256, 0, stream>>>(qkv_w, qkv_wt, 512, 1536);
    wtrans_kernel<<<dim3(512 / 32, 512 / 32, NDEPTH), 256, 0, stream>>>(out_w, out_wt, 512, 512);
    wtrans_kernel<<<dim3(2048 / 32, 512 / 32, NDEPTH), 256, 0, stream>>>(ff1_w, ff1_wt, 512, 2048);
    wtrans_kernel<<<dim3(512 / 32, 2048 / 32, NDEPTH), 256, 0, stream>>>(ff2_w, ff2_wt, 2048, 512);
    pwt_kernel<<<DIM, 256, 0, stream>>>(patch_w, pwt);

    // patch embed = im2col + GEMM + pos add
    im2col_kernel<<<MPAD, 256, 0, stream>>>(img, pcol);
    gemm_bf16_kernel<64><<<dim3(DIM / 128, MPAD / 64), 256, 0, stream>>>(
        pcol, pwt, patch_b, nullptr, x, DIM, PKD, 3);
    pos_add_kernel<<<ROWS, 256, 0, stream>>>(x, cls_token, pos_emb);

    for (int l = 0; l < NDEPTH; ++l) {
        ln4_kernel<<<ROWS / 4, 256, 0, stream>>>(x, hb, ln1_w + l * DIM, ln1_b + l * DIM);
        gemm_bf16_kernel<128><<<dim3(1536 / 128, MPAD / 128), 256, 0, stream>>>(
            hb, qkv_wt + (size_t)l * 1536 * 512, nullptr, qkvb, nullptr, 1536, 512, 0);
        qk_softmax_kernel<<<dim3(BATCH * NHEADS, 2), 256, 0, stream>>>(qkvb, P);
        mix_ln_kernel<<<dim3(SEQ, BATCH), 256, 0, stream>>>(
            P, reattn_w + l * 64, reattn_lw + l * 8, reattn_lb + l * 8, Pm);
        av_kernel<<<dim3(BATCH * NHEADS, 2), 256, 0, stream>>>(Pm, qkvb, hb);
        gemm_bf16_kernel<64><<<dim3(DIM / 128, MPAD / 64), 256, 0, stream>>>(
            hb, out_wt + (size_t)l * 512 * 512, out_b + l * DIM, nullptr, x, DIM, 512, 1);
        ln4_kernel<<<ROWS / 4, 256, 0, stream>>>(x, hb, ln2_w + l * DIM, ln2_b + l * DIM);
        gemm_bf16_kernel<128><<<dim3(MLPD / 128, MPAD / 128), 256, 0, stream>>>(
            hb, ff1_wt + (size_t)l * 2048 * 512, ff1_b + l * MLPD, midb, nullptr, MLPD, 512, 2);
        gemm_bf16_kernel<64><<<dim3(DIM / 128, MPAD / 64), 256, 0, stream>>>(
            midb, ff2_wt + (size_t)l * 512 * 2048, ff2_b + l * DIM, nullptr, x, DIM, 2048, 1);
    }

    ln_kernel<<<BATCH, 256, 0, stream>>>(x, out, head_lw, head_lb, (size_t)SEQ * DIM, DIM);
}